// Round 2
// baseline (597.035 us; speedup 1.0000x reference)
//
#include <hip/hip_runtime.h>
#include <math.h>

#define D 512
#define BATCH 256

typedef float f4 __attribute__((ext_vector_type(4)));

// ---------------- kernel 1: projections Y = X @ W^T (+ sigmoid/bias for o) ----
// X [256,512], W [512,512] row-major. BM=BN=64, BK=32, 256 threads, 4x4 micro.
// (unchanged from verified baseline — ~20 us, not the bottleneck this round)
__global__ __launch_bounds__(256) void proj_gemm(
    const float* __restrict__ X,
    const float* __restrict__ Wq, const float* __restrict__ Wk,
    const float* __restrict__ Wv, const float* __restrict__ Wo,
    const float* __restrict__ Wo_b,
    float* __restrict__ qb, float* __restrict__ kb,
    float* __restrict__ vb, float* __restrict__ ob)
{
    const int mat = blockIdx.z;
    const float* W = (mat == 0) ? Wq : (mat == 1) ? Wk : (mat == 2) ? Wv : Wo;
    float* Y = (mat == 0) ? qb : (mat == 1) ? kb : (mat == 2) ? vb : ob;

    const int m0 = blockIdx.y * 64;
    const int n0 = blockIdx.x * 64;

    __shared__ float Xs[64][33];
    __shared__ float Ws[64][33];

    const int t = threadIdx.x;
    const int lr = t >> 3;          // 0..31 (tile row for loading)
    const int lc = (t & 7) * 4;     // k offset 0,4,..,28
    const int ty = t >> 4;          // 0..15
    const int tx = t & 15;          // 0..15

    float acc[4][4] = {};

    for (int k0 = 0; k0 < D; k0 += 32) {
        float4 xa = *(const float4*)&X[(size_t)(m0 + lr) * D + k0 + lc];
        float4 xb = *(const float4*)&X[(size_t)(m0 + lr + 32) * D + k0 + lc];
        float4 wa = *(const float4*)&W[(size_t)(n0 + lr) * D + k0 + lc];
        float4 wb = *(const float4*)&W[(size_t)(n0 + lr + 32) * D + k0 + lc];
        __syncthreads();
        Xs[lr][lc + 0] = xa.x; Xs[lr][lc + 1] = xa.y; Xs[lr][lc + 2] = xa.z; Xs[lr][lc + 3] = xa.w;
        Xs[lr + 32][lc + 0] = xb.x; Xs[lr + 32][lc + 1] = xb.y; Xs[lr + 32][lc + 2] = xb.z; Xs[lr + 32][lc + 3] = xb.w;
        Ws[lr][lc + 0] = wa.x; Ws[lr][lc + 1] = wa.y; Ws[lr][lc + 2] = wa.z; Ws[lr][lc + 3] = wa.w;
        Ws[lr + 32][lc + 0] = wb.x; Ws[lr + 32][lc + 1] = wb.y; Ws[lr + 32][lc + 2] = wb.z; Ws[lr + 32][lc + 3] = wb.w;
        __syncthreads();
#pragma unroll
        for (int kk = 0; kk < 32; ++kk) {
            float a0 = Xs[ty * 4 + 0][kk];
            float a1 = Xs[ty * 4 + 1][kk];
            float a2 = Xs[ty * 4 + 2][kk];
            float a3 = Xs[ty * 4 + 3][kk];
            float b0 = Ws[tx * 4 + 0][kk];
            float b1 = Ws[tx * 4 + 1][kk];
            float b2 = Ws[tx * 4 + 2][kk];
            float b3 = Ws[tx * 4 + 3][kk];
            acc[0][0] += a0 * b0; acc[0][1] += a0 * b1; acc[0][2] += a0 * b2; acc[0][3] += a0 * b3;
            acc[1][0] += a1 * b0; acc[1][1] += a1 * b1; acc[1][2] += a1 * b2; acc[1][3] += a1 * b3;
            acc[2][0] += a2 * b0; acc[2][1] += a2 * b1; acc[2][2] += a2 * b2; acc[2][3] += a2 * b3;
            acc[3][0] += a3 * b0; acc[3][1] += a3 * b1; acc[3][2] += a3 * b2; acc[3][3] += a3 * b3;
        }
    }

#pragma unroll
    for (int i = 0; i < 4; ++i) {
        int row = m0 + ty * 4 + i;
#pragma unroll
        for (int j = 0; j < 4; ++j) {
            int col = n0 + tx * 4 + j;
            float y = acc[i][j];
            if (mat == 3) y = 1.0f / (1.0f + expf(-(y + Wo_b[col])));
            Y[(size_t)row * D + col] = y;
        }
    }
}

// ---------------- block reduce for 1024 threads (16 waves) -------------------
__device__ __forceinline__ float blockReduceSum16(float val, float* red) {
#pragma unroll
    for (int off = 32; off > 0; off >>= 1)
        val += __shfl_down(val, off, 64);
    const int lane = threadIdx.x & 63;
    const int w = threadIdx.x >> 6;
    __syncthreads();
    if (lane == 0) red[w] = val;
    __syncthreads();
    float s = 0.0f;
#pragma unroll
    for (int i = 0; i < 16; ++i) s += red[i];
    return s;
}

// ---------------- kernel 2: mega — gates + n_t + C update + retrieval + LN ---
// One block per batch element b; 16 waves; wave w owns rows 16j+w.
// THIS ROUND: cross-lane dot reductions DEFERRED out of the streaming loop.
// Loop body is pure load->fma->NT-store->fma(acc), fully unrolled with
// statically-indexed acc[32]/av[32] (dynamic-indexed arrays go to scratch).
// C_prev loads are REGULAR (re-read next iteration; let L2/L3 keep it);
// out_C stores stay non-temporal (write-once dead stream, don't evict).
__global__ __launch_bounds__(1024) void mega(
    const float* __restrict__ x, const float* __restrict__ n_prev,
    const float* __restrict__ C_prev,
    const float* __restrict__ wi_w, const float* __restrict__ wi_b,
    const float* __restrict__ wf_w, const float* __restrict__ wf_b,
    const float* __restrict__ qb, const float* __restrict__ kb,
    const float* __restrict__ vb, const float* __restrict__ ob,
    const float* __restrict__ ln_g, const float* __restrict__ ln_be,
    float* __restrict__ out_h, float* __restrict__ out_C,
    float* __restrict__ out_n)
{
    __shared__ float red[16];
    __shared__ float hs[D];

    const int b = blockIdx.x;
    const int t = threadIdx.x;
    const int lane = t & 63;
    const int w = t >> 6;           // wave id 0..15

    const size_t bD = (size_t)b * D;

    // ---- gates i_t, f_t (x . wi_w, x . wf_w) ----
    float si = 0.0f, sf = 0.0f;
    if (t < D) {
        float xv = x[bD + t];
        si = xv * wi_w[t];
        sf = xv * wf_w[t];
    }
    si = blockReduceSum16(si, red);
    sf = blockReduceSum16(sf, red);
    const float i_t = fminf(expf(si + wi_b[0]), 50.0f);
    const float f_t = 1.0f / (1.0f + expf(-(sf + wf_b[0])));

    // ---- n_t and nq ----
    float nq_p = 0.0f;
    if (t < D) {
        float nv = f_t * n_prev[bD + t] + i_t * kb[bD + t];
        out_n[bD + t] = nv;
        nq_p = nv * qb[bD + t];
    }
    const float nq = blockReduceSum16(nq_p, red);
    const float invnq = 1.0f / fmaxf(fabsf(nq), 1.0f);

    // ---- k, q resident in registers ----
    const f4* k4 = (const f4*)(kb + bD);
    const f4* q4 = (const f4*)(qb + bD);
    const f4 ka = k4[lane], kc = k4[lane + 64];
    const f4 qa = q4[lane], qc = q4[lane + 64];

    const float* vrow = vb + bD;
    const float* orow = ob + bD;
    const f4* Cp = (const f4*)(C_prev + bD * D);
    f4*       Ct = (f4*)(out_C + bD * D);

    // ---- per-row scale a = i_t * v[r], preloaded (broadcast loads) ----
    float av[32];
#pragma unroll
    for (int j = 0; j < 32; ++j)
        av[j] = i_t * vrow[(j << 4) + w];

    // ---- pure streaming loop: no cross-lane ops, no LDS, no barriers ----
    float acc[32];
#pragma unroll
    for (int j = 0; j < 32; ++j) {
        const int r = (j << 4) + w;
        const f4* cpr = Cp + (size_t)r * (D / 4);
        f4 c0 = cpr[lane];
        f4 c1 = cpr[lane + 64];
        f4 r0 = f_t * c0 + av[j] * ka;
        f4 r1 = f_t * c1 + av[j] * kc;
        f4* ctr = Ct + (size_t)r * (D / 4);
        __builtin_nontemporal_store(r0, ctr + lane);
        __builtin_nontemporal_store(r1, ctr + lane + 64);
        f4 m = r0 * qa + r1 * qc;
        acc[j] = m.x + m.y + m.z + m.w;
    }

    // ---- deferred cross-lane reductions (off the memory path) ----
#pragma unroll
    for (int j = 0; j < 32; ++j) {
        float d = acc[j];
#pragma unroll
        for (int off = 32; off > 0; off >>= 1)
            d += __shfl_down(d, off, 64);
        if (lane == 0) {
            const int r = (j << 4) + w;
            hs[r] = d * orow[r] * invnq;
        }
    }

    // ---- LayerNorm epilogue (in-block; hs has all 512 values) ----
    __syncthreads();
    float h0 = (t < D) ? hs[t] : 0.0f;
    const float mu = blockReduceSum16(h0, red) * (1.0f / 512.0f);
    const float d0 = (t < D) ? (h0 - mu) : 0.0f;
    const float var = blockReduceSum16(d0 * d0, red) * (1.0f / 512.0f);
    const float rstd = rsqrtf(var + 1e-5f);
    if (t < D)
        out_h[bD + t] = d0 * rstd * ln_g[t] + ln_be[t];
}

// ---------------- launcher ----------------------------------------------------
extern "C" void kernel_launch(void* const* d_in, const int* in_sizes, int n_in,
                              void* d_out, int out_size, void* d_ws, size_t ws_size,
                              hipStream_t stream) {
    const float* x_t    = (const float*)d_in[0];
    const float* C_prev = (const float*)d_in[1];
    const float* n_prev = (const float*)d_in[2];
    const float* Wq     = (const float*)d_in[3];
    const float* Wk     = (const float*)d_in[4];
    const float* Wv     = (const float*)d_in[5];
    const float* wi_w   = (const float*)d_in[6];
    const float* wi_b   = (const float*)d_in[7];
    const float* wf_w   = (const float*)d_in[8];
    const float* wf_b   = (const float*)d_in[9];
    const float* Wo_w   = (const float*)d_in[10];
    const float* Wo_b   = (const float*)d_in[11];
    const float* ln_g   = (const float*)d_in[12];
    const float* ln_b   = (const float*)d_in[13];

    float* out = (float*)d_out;
    float* out_h = out;                                  // [256,512]
    float* out_C = out + (size_t)BATCH * D;              // [256,512,512]
    float* out_n = out + (size_t)BATCH * D + (size_t)BATCH * D * D; // [256,512]

    float* ws = (float*)d_ws;
    const size_t BD = (size_t)BATCH * D;                 // 131072
    float* qb = ws;
    float* kb = ws + BD;
    float* vb = ws + 2 * BD;
    float* ob = ws + 3 * BD;

    // 1) projections q,k,v,o (o fused with sigmoid+bias)
    proj_gemm<<<dim3(D / 64, BATCH / 64, 4), 256, 0, stream>>>(
        x_t, Wq, Wk, Wv, Wo_w, Wo_b, qb, kb, vb, ob);

    // 2) everything else, fused: gates + n_t + nq + C update + retrieval + LN
    mega<<<dim3(BATCH), 1024, 0, stream>>>(
        x_t, n_prev, C_prev, wi_w, wi_b, wf_w, wf_b,
        qb, kb, vb, ob, ln_g, ln_b, out_h, out_n ? out_C : out_C, out_n);
}

// Round 3
// 520.793 us; speedup vs baseline: 1.1464x; 1.1464x over previous
//
#include <hip/hip_runtime.h>
#include <math.h>

#define D 512
#define BATCH 256

typedef float f4 __attribute__((ext_vector_type(4)));

// ---------------- kernel 1: projections Y = X @ W^T (+ sigmoid/bias for o) ----
// X [256,512], W [512,512] row-major. BM=BN=64, BK=32, 256 threads, 4x4 micro.
// (unchanged from verified baseline — ~20 us, not the bottleneck)
__global__ __launch_bounds__(256) void proj_gemm(
    const float* __restrict__ X,
    const float* __restrict__ Wq, const float* __restrict__ Wk,
    const float* __restrict__ Wv, const float* __restrict__ Wo,
    const float* __restrict__ Wo_b,
    float* __restrict__ qb, float* __restrict__ kb,
    float* __restrict__ vb, float* __restrict__ ob)
{
    const int mat = blockIdx.z;
    const float* W = (mat == 0) ? Wq : (mat == 1) ? Wk : (mat == 2) ? Wv : Wo;
    float* Y = (mat == 0) ? qb : (mat == 1) ? kb : (mat == 2) ? vb : ob;

    const int m0 = blockIdx.y * 64;
    const int n0 = blockIdx.x * 64;

    __shared__ float Xs[64][33];
    __shared__ float Ws[64][33];

    const int t = threadIdx.x;
    const int lr = t >> 3;          // 0..31 (tile row for loading)
    const int lc = (t & 7) * 4;     // k offset 0,4,..,28
    const int ty = t >> 4;          // 0..15
    const int tx = t & 15;          // 0..15

    float acc[4][4] = {};

    for (int k0 = 0; k0 < D; k0 += 32) {
        float4 xa = *(const float4*)&X[(size_t)(m0 + lr) * D + k0 + lc];
        float4 xb = *(const float4*)&X[(size_t)(m0 + lr + 32) * D + k0 + lc];
        float4 wa = *(const float4*)&W[(size_t)(n0 + lr) * D + k0 + lc];
        float4 wb = *(const float4*)&W[(size_t)(n0 + lr + 32) * D + k0 + lc];
        __syncthreads();
        Xs[lr][lc + 0] = xa.x; Xs[lr][lc + 1] = xa.y; Xs[lr][lc + 2] = xa.z; Xs[lr][lc + 3] = xa.w;
        Xs[lr + 32][lc + 0] = xb.x; Xs[lr + 32][lc + 1] = xb.y; Xs[lr + 32][lc + 2] = xb.z; Xs[lr + 32][lc + 3] = xb.w;
        Ws[lr][lc + 0] = wa.x; Ws[lr][lc + 1] = wa.y; Ws[lr][lc + 2] = wa.z; Ws[lr][lc + 3] = wa.w;
        Ws[lr + 32][lc + 0] = wb.x; Ws[lr + 32][lc + 1] = wb.y; Ws[lr + 32][lc + 2] = wb.z; Ws[lr + 32][lc + 3] = wb.w;
        __syncthreads();
#pragma unroll
        for (int kk = 0; kk < 32; ++kk) {
            float a0 = Xs[ty * 4 + 0][kk];
            float a1 = Xs[ty * 4 + 1][kk];
            float a2 = Xs[ty * 4 + 2][kk];
            float a3 = Xs[ty * 4 + 3][kk];
            float b0 = Ws[tx * 4 + 0][kk];
            float b1 = Ws[tx * 4 + 1][kk];
            float b2 = Ws[tx * 4 + 2][kk];
            float b3 = Ws[tx * 4 + 3][kk];
            acc[0][0] += a0 * b0; acc[0][1] += a0 * b1; acc[0][2] += a0 * b2; acc[0][3] += a0 * b3;
            acc[1][0] += a1 * b0; acc[1][1] += a1 * b1; acc[1][2] += a1 * b2; acc[1][3] += a1 * b3;
            acc[2][0] += a2 * b0; acc[2][1] += a2 * b1; acc[2][2] += a2 * b2; acc[2][3] += a2 * b3;
            acc[3][0] += a3 * b0; acc[3][1] += a3 * b1; acc[3][2] += a3 * b2; acc[3][3] += a3 * b3;
        }
    }

#pragma unroll
    for (int i = 0; i < 4; ++i) {
        int row = m0 + ty * 4 + i;
#pragma unroll
        for (int j = 0; j < 4; ++j) {
            int col = n0 + tx * 4 + j;
            float y = acc[i][j];
            if (mat == 3) y = 1.0f / (1.0f + expf(-(y + Wo_b[col])));
            Y[(size_t)row * D + col] = y;
        }
    }
}

// ---------------- block reduce for 1024 threads (16 waves) -------------------
__device__ __forceinline__ float blockReduceSum16(float val, float* red) {
#pragma unroll
    for (int off = 32; off > 0; off >>= 1)
        val += __shfl_down(val, off, 64);
    const int lane = threadIdx.x & 63;
    const int w = threadIdx.x >> 6;
    __syncthreads();
    if (lane == 0) red[w] = val;
    __syncthreads();
    float s = 0.0f;
#pragma unroll
    for (int i = 0; i < 16; ++i) s += red[i];
    return s;
}

// ---------------- kernel 2: mega — gates + n_t + C update + retrieval + LN ---
// One block per batch element b; 16 waves = 4 waves/EU = 1 block/CU
// (__launch_bounds__(1024,4) -> allocator may use up to 128 VGPRs: r2's
// full 32-row unroll at 64 VGPRs spilled 160MB to scratch, the regression).
// Streaming loop: GROUPS OF 8 rows, pure load->fma->NT-store; the 8
// cross-lane reductions run AFTER each group as 8 independent chains
// (ILP hides the 6-step shuffle latency; off the memory path).
// C_prev loads regular (L3 retains ~50MB/iter across launches: FETCH 217<268MB);
// out_C stores non-temporal (write-once dead stream, don't evict C_prev).
__global__ __launch_bounds__(1024, 4) void mega(
    const float* __restrict__ x, const float* __restrict__ n_prev,
    const float* __restrict__ C_prev,
    const float* __restrict__ wi_w, const float* __restrict__ wi_b,
    const float* __restrict__ wf_w, const float* __restrict__ wf_b,
    const float* __restrict__ qb, const float* __restrict__ kb,
    const float* __restrict__ vb, const float* __restrict__ ob,
    const float* __restrict__ ln_g, const float* __restrict__ ln_be,
    float* __restrict__ out_h, float* __restrict__ out_C,
    float* __restrict__ out_n)
{
    __shared__ float red[16];
    __shared__ float hs[D];

    const int b = blockIdx.x;
    const int t = threadIdx.x;
    const int lane = t & 63;
    const int w = t >> 6;           // wave id 0..15

    const size_t bD = (size_t)b * D;

    // ---- gates i_t, f_t (x . wi_w, x . wf_w) ----
    float si = 0.0f, sf = 0.0f;
    if (t < D) {
        float xv = x[bD + t];
        si = xv * wi_w[t];
        sf = xv * wf_w[t];
    }
    si = blockReduceSum16(si, red);
    sf = blockReduceSum16(sf, red);
    const float i_t = fminf(expf(si + wi_b[0]), 50.0f);
    const float f_t = 1.0f / (1.0f + expf(-(sf + wf_b[0])));

    // ---- n_t and nq ----
    float nq_p = 0.0f;
    if (t < D) {
        float nv = f_t * n_prev[bD + t] + i_t * kb[bD + t];
        out_n[bD + t] = nv;
        nq_p = nv * qb[bD + t];
    }
    const float nq = blockReduceSum16(nq_p, red);
    const float invnq = 1.0f / fmaxf(fabsf(nq), 1.0f);

    // ---- k, q resident in registers ----
    const f4* k4 = (const f4*)(kb + bD);
    const f4* q4 = (const f4*)(qb + bD);
    const f4 ka = k4[lane], kc = k4[lane + 64];
    const f4 qa = q4[lane], qc = q4[lane + 64];

    const float* vrow = vb + bD;
    const float* orow = ob + bD;
    const f4* Cp = (const f4*)(C_prev + bD * D);
    f4*       Ct = (f4*)(out_C + bD * D);

    // ---- 4 groups x 8 rows per wave; wave w owns rows 16j+w ----
#pragma unroll
    for (int g = 0; g < 4; ++g) {
        float av[8], acc[8];
#pragma unroll
        for (int e = 0; e < 8; ++e)
            av[e] = i_t * vrow[(((g << 3) + e) << 4) + w];

        // pure streaming: no cross-lane ops, no LDS, no barriers
#pragma unroll
        for (int e = 0; e < 8; ++e) {
            const int r = (((g << 3) + e) << 4) + w;
            const f4* cpr = Cp + (size_t)r * (D / 4);
            f4 c0 = cpr[lane];
            f4 c1 = cpr[lane + 64];
            f4 r0 = f_t * c0 + av[e] * ka;
            f4 r1 = f_t * c1 + av[e] * kc;
            f4* ctr = Ct + (size_t)r * (D / 4);
            __builtin_nontemporal_store(r0, ctr + lane);
            __builtin_nontemporal_store(r1, ctr + lane + 64);
            f4 m = r0 * qa + r1 * qc;
            acc[e] = m.x + m.y + m.z + m.w;
        }

        // 8 independent reduction chains — ILP hides shuffle latency
#pragma unroll
        for (int off = 32; off > 0; off >>= 1) {
#pragma unroll
            for (int e = 0; e < 8; ++e)
                acc[e] += __shfl_down(acc[e], off, 64);
        }
        if (lane == 0) {
#pragma unroll
            for (int e = 0; e < 8; ++e) {
                const int r = (((g << 3) + e) << 4) + w;
                hs[r] = acc[e] * orow[r] * invnq;
            }
        }
    }

    // ---- LayerNorm epilogue (in-block; hs has all 512 values) ----
    __syncthreads();
    float h0 = (t < D) ? hs[t] : 0.0f;
    const float mu = blockReduceSum16(h0, red) * (1.0f / 512.0f);
    const float d0 = (t < D) ? (h0 - mu) : 0.0f;
    const float var = blockReduceSum16(d0 * d0, red) * (1.0f / 512.0f);
    const float rstd = rsqrtf(var + 1e-5f);
    if (t < D)
        out_h[bD + t] = d0 * rstd * ln_g[t] + ln_be[t];
}

// ---------------- launcher ----------------------------------------------------
extern "C" void kernel_launch(void* const* d_in, const int* in_sizes, int n_in,
                              void* d_out, int out_size, void* d_ws, size_t ws_size,
                              hipStream_t stream) {
    const float* x_t    = (const float*)d_in[0];
    const float* C_prev = (const float*)d_in[1];
    const float* n_prev = (const float*)d_in[2];
    const float* Wq     = (const float*)d_in[3];
    const float* Wk     = (const float*)d_in[4];
    const float* Wv     = (const float*)d_in[5];
    const float* wi_w   = (const float*)d_in[6];
    const float* wi_b   = (const float*)d_in[7];
    const float* wf_w   = (const float*)d_in[8];
    const float* wf_b   = (const float*)d_in[9];
    const float* Wo_w   = (const float*)d_in[10];
    const float* Wo_b   = (const float*)d_in[11];
    const float* ln_g   = (const float*)d_in[12];
    const float* ln_b   = (const float*)d_in[13];

    float* out = (float*)d_out;
    float* out_h = out;                                  // [256,512]
    float* out_C = out + (size_t)BATCH * D;              // [256,512,512]
    float* out_n = out + (size_t)BATCH * D + (size_t)BATCH * D * D; // [256,512]

    float* ws = (float*)d_ws;
    const size_t BD = (size_t)BATCH * D;                 // 131072
    float* qb = ws;
    float* kb = ws + BD;
    float* vb = ws + 2 * BD;
    float* ob = ws + 3 * BD;

    // 1) projections q,k,v,o (o fused with sigmoid+bias)
    proj_gemm<<<dim3(D / 64, BATCH / 64, 4), 256, 0, stream>>>(
        x_t, Wq, Wk, Wv, Wo_w, Wo_b, qb, kb, vb, ob);

    // 2) everything else, fused: gates + n_t + nq + C update + retrieval + LN
    mega<<<dim3(BATCH), 1024, 0, stream>>>(
        x_t, n_prev, C_prev, wi_w, wi_b, wf_w, wf_b,
        qb, kb, vb, ob, ln_g, ln_b, out_h, out_C, out_n);
}

// Round 4
// 518.799 us; speedup vs baseline: 1.1508x; 1.0038x over previous
//
#include <hip/hip_runtime.h>
#include <math.h>

#define D 512
#define BATCH 256

typedef float f4 __attribute__((ext_vector_type(4)));

// ---------------- kernel 1: projections Y = X @ W^T (+ sigmoid/bias for o) ----
// X [256,512], W [512,512] row-major. BM=BN=64, BK=32, 256 threads, 4x4 micro.
// (unchanged from verified baseline — ~20 us, not the bottleneck)
__global__ __launch_bounds__(256) void proj_gemm(
    const float* __restrict__ X,
    const float* __restrict__ Wq, const float* __restrict__ Wk,
    const float* __restrict__ Wv, const float* __restrict__ Wo,
    const float* __restrict__ Wo_b,
    float* __restrict__ qb, float* __restrict__ kb,
    float* __restrict__ vb, float* __restrict__ ob)
{
    const int mat = blockIdx.z;
    const float* W = (mat == 0) ? Wq : (mat == 1) ? Wk : (mat == 2) ? Wv : Wo;
    float* Y = (mat == 0) ? qb : (mat == 1) ? kb : (mat == 2) ? vb : ob;

    const int m0 = blockIdx.y * 64;
    const int n0 = blockIdx.x * 64;

    __shared__ float Xs[64][33];
    __shared__ float Ws[64][33];

    const int t = threadIdx.x;
    const int lr = t >> 3;          // 0..31 (tile row for loading)
    const int lc = (t & 7) * 4;     // k offset 0,4,..,28
    const int ty = t >> 4;          // 0..15
    const int tx = t & 15;          // 0..15

    float acc[4][4] = {};

    for (int k0 = 0; k0 < D; k0 += 32) {
        float4 xa = *(const float4*)&X[(size_t)(m0 + lr) * D + k0 + lc];
        float4 xb = *(const float4*)&X[(size_t)(m0 + lr + 32) * D + k0 + lc];
        float4 wa = *(const float4*)&W[(size_t)(n0 + lr) * D + k0 + lc];
        float4 wb = *(const float4*)&W[(size_t)(n0 + lr + 32) * D + k0 + lc];
        __syncthreads();
        Xs[lr][lc + 0] = xa.x; Xs[lr][lc + 1] = xa.y; Xs[lr][lc + 2] = xa.z; Xs[lr][lc + 3] = xa.w;
        Xs[lr + 32][lc + 0] = xb.x; Xs[lr + 32][lc + 1] = xb.y; Xs[lr + 32][lc + 2] = xb.z; Xs[lr + 32][lc + 3] = xb.w;
        Ws[lr][lc + 0] = wa.x; Ws[lr][lc + 1] = wa.y; Ws[lr][lc + 2] = wa.z; Ws[lr][lc + 3] = wa.w;
        Ws[lr + 32][lc + 0] = wb.x; Ws[lr + 32][lc + 1] = wb.y; Ws[lr + 32][lc + 2] = wb.z; Ws[lr + 32][lc + 3] = wb.w;
        __syncthreads();
#pragma unroll
        for (int kk = 0; kk < 32; ++kk) {
            float a0 = Xs[ty * 4 + 0][kk];
            float a1 = Xs[ty * 4 + 1][kk];
            float a2 = Xs[ty * 4 + 2][kk];
            float a3 = Xs[ty * 4 + 3][kk];
            float b0 = Ws[tx * 4 + 0][kk];
            float b1 = Ws[tx * 4 + 1][kk];
            float b2 = Ws[tx * 4 + 2][kk];
            float b3 = Ws[tx * 4 + 3][kk];
            acc[0][0] += a0 * b0; acc[0][1] += a0 * b1; acc[0][2] += a0 * b2; acc[0][3] += a0 * b3;
            acc[1][0] += a1 * b0; acc[1][1] += a1 * b1; acc[1][2] += a1 * b2; acc[1][3] += a1 * b3;
            acc[2][0] += a2 * b0; acc[2][1] += a2 * b1; acc[2][2] += a2 * b2; acc[2][3] += a2 * b3;
            acc[3][0] += a3 * b0; acc[3][1] += a3 * b1; acc[3][2] += a3 * b2; acc[3][3] += a3 * b3;
        }
    }

#pragma unroll
    for (int i = 0; i < 4; ++i) {
        int row = m0 + ty * 4 + i;
#pragma unroll
        for (int j = 0; j < 4; ++j) {
            int col = n0 + tx * 4 + j;
            float y = acc[i][j];
            if (mat == 3) y = 1.0f / (1.0f + expf(-(y + Wo_b[col])));
            Y[(size_t)row * D + col] = y;
        }
    }
}

// ---------------- block reduce (256 threads = 4 waves) ----------------
__device__ __forceinline__ float blockReduceSum(float val, float* smem) {
#pragma unroll
    for (int off = 32; off > 0; off >>= 1)
        val += __shfl_down(val, off, 64);
    int lane = threadIdx.x & 63;
    int w = threadIdx.x >> 6;
    __syncthreads();
    if (lane == 0) smem[w] = val;
    __syncthreads();
    return smem[0] + smem[1] + smem[2] + smem[3];
}

// ---------------- kernel 2: cstream — gates + n_t + C update + retrieval -----
// TLP is the lever (r3 post-mortem): 2048 blocks x 256 thr -> 8 blocks/CU,
// 32 waves/CU resident (vs mega's 16). Each block: batch b = bid>>3, rows
// [chunk*64, +64); wave w owns 16 rows. k,q in registers (loaded once/wave).
// Gates/n_t/nq recomputed per block (inputs L2-hot, ~1us total); n_t written
// by chunk 0 only. Streaming: groups of 2 rows, pure load->fma->NT-store,
// then 2 deferred shuffle chains (paired for ILP). C_prev loads regular
// (L3 retention: r3 FETCH was 135MB < 268MB); out_C stores non-temporal.
__global__ __launch_bounds__(256, 8) void cstream(
    const float* __restrict__ x, const float* __restrict__ n_prev,
    const float* __restrict__ C_prev,
    const float* __restrict__ wi_w, const float* __restrict__ wi_b,
    const float* __restrict__ wf_w, const float* __restrict__ wf_b,
    const float* __restrict__ qb, const float* __restrict__ kb,
    const float* __restrict__ vb, const float* __restrict__ ob,
    float* __restrict__ out_C, float* __restrict__ out_n,
    float* __restrict__ h_pre)
{
    __shared__ float red[4];
    const int bid = blockIdx.x;
    const int b = bid >> 3;
    const int chunk = bid & 7;
    const int t = threadIdx.x;
    const int lane = t & 63;
    const int w = t >> 6;            // wave 0..3

    const size_t bD = (size_t)b * D;

    // ---- gates i_t, f_t ----
    const float* xb = x + bD;
    float x0 = xb[t], x1 = xb[t + 256];
    float si = x0 * wi_w[t] + x1 * wi_w[t + 256];
    float sf = x0 * wf_w[t] + x1 * wf_w[t + 256];
    si = blockReduceSum(si, red);
    sf = blockReduceSum(sf, red);
    const float i_t = fminf(expf(si + wi_b[0]), 50.0f);
    const float f_t = 1.0f / (1.0f + expf(-(sf + wf_b[0])));

    // ---- n_t + nq ----
    const float* npv = n_prev + bD;
    const float* kk = kb + bD;
    const float* qq = qb + bD;
    float n0 = f_t * npv[t] + i_t * kk[t];
    float n1 = f_t * npv[t + 256] + i_t * kk[t + 256];
    if (chunk == 0) {
        out_n[bD + t] = n0;
        out_n[bD + t + 256] = n1;
    }
    float nq = blockReduceSum(n0 * qq[t] + n1 * qq[t + 256], red);
    const float invnq = 1.0f / fmaxf(fabsf(nq), 1.0f);

    // ---- k, q resident in registers (full 512-vec across lane, lane+64) ----
    const f4* k4 = (const f4*)(kb + bD);
    const f4* q4 = (const f4*)(qb + bD);
    const f4 ka = k4[lane], kc = k4[lane + 64];
    const f4 qa = q4[lane], qc = q4[lane + 64];

    const float* vrow = vb + bD;
    const float* orow = ob + bD;
    const f4* Cp = (const f4*)(C_prev + bD * D);
    f4*       Ct = (f4*)(out_C + bD * D);

    const int row0 = chunk * 64 + w * 16;

#pragma unroll 2
    for (int g = 0; g < 8; ++g) {
        const int ra = row0 + 2 * g;
        float av0 = i_t * vrow[ra];
        float av1 = i_t * vrow[ra + 1];

        // pure streaming, 2 rows: 4 loads in flight, no cross-lane ops
        const f4* cpr0 = Cp + (size_t)ra * 128;
        const f4* cpr1 = Cp + (size_t)(ra + 1) * 128;
        f4 c00 = cpr0[lane], c01 = cpr0[lane + 64];
        f4 c10 = cpr1[lane], c11 = cpr1[lane + 64];
        f4 r00 = f_t * c00 + av0 * ka;
        f4 r01 = f_t * c01 + av0 * kc;
        f4 r10 = f_t * c10 + av1 * ka;
        f4 r11 = f_t * c11 + av1 * kc;
        f4* ctr0 = Ct + (size_t)ra * 128;
        f4* ctr1 = Ct + (size_t)(ra + 1) * 128;
        __builtin_nontemporal_store(r00, ctr0 + lane);
        __builtin_nontemporal_store(r01, ctr0 + lane + 64);
        __builtin_nontemporal_store(r10, ctr1 + lane);
        __builtin_nontemporal_store(r11, ctr1 + lane + 64);
        f4 m0 = r00 * qa + r01 * qc;
        f4 m1 = r10 * qa + r11 * qc;
        float acc0 = m0.x + m0.y + m0.z + m0.w;
        float acc1 = m1.x + m1.y + m1.z + m1.w;

        // two independent shuffle chains (ILP)
#pragma unroll
        for (int off = 32; off > 0; off >>= 1) {
            acc0 += __shfl_down(acc0, off, 64);
            acc1 += __shfl_down(acc1, off, 64);
        }
        if (lane == 0) {
            h_pre[bD + ra]     = acc0 * orow[ra]     * invnq;
            h_pre[bD + ra + 1] = acc1 * orow[ra + 1] * invnq;
        }
    }
}

// ---------------- kernel 3: LayerNorm epilogue (one block per b) --------------
__global__ __launch_bounds__(256) void ln_kernel(
    const float* __restrict__ h_pre,
    const float* __restrict__ g, const float* __restrict__ be,
    float* __restrict__ out_h)
{
    __shared__ float red[4];
    const int b = blockIdx.x;
    const int t = threadIdx.x;
    const float* h = h_pre + (size_t)b * D;
    float h0 = h[t], h1 = h[t + 256];
    float mu = blockReduceSum(h0 + h1, red) * (1.0f / 512.0f);
    float d0 = h0 - mu, d1 = h1 - mu;
    float var = blockReduceSum(d0 * d0 + d1 * d1, red) * (1.0f / 512.0f);
    float rstd = rsqrtf(var + 1e-5f);
    out_h[(size_t)b * D + t] = d0 * rstd * g[t] + be[t];
    out_h[(size_t)b * D + t + 256] = d1 * rstd * g[t + 256] + be[t + 256];
}

// ---------------- launcher ----------------------------------------------------
extern "C" void kernel_launch(void* const* d_in, const int* in_sizes, int n_in,
                              void* d_out, int out_size, void* d_ws, size_t ws_size,
                              hipStream_t stream) {
    const float* x_t    = (const float*)d_in[0];
    const float* C_prev = (const float*)d_in[1];
    const float* n_prev = (const float*)d_in[2];
    const float* Wq     = (const float*)d_in[3];
    const float* Wk     = (const float*)d_in[4];
    const float* Wv     = (const float*)d_in[5];
    const float* wi_w   = (const float*)d_in[6];
    const float* wi_b   = (const float*)d_in[7];
    const float* wf_w   = (const float*)d_in[8];
    const float* wf_b   = (const float*)d_in[9];
    const float* Wo_w   = (const float*)d_in[10];
    const float* Wo_b   = (const float*)d_in[11];
    const float* ln_g   = (const float*)d_in[12];
    const float* ln_b   = (const float*)d_in[13];

    float* out = (float*)d_out;
    float* out_h = out;                                  // [256,512]
    float* out_C = out + (size_t)BATCH * D;              // [256,512,512]
    float* out_n = out + (size_t)BATCH * D + (size_t)BATCH * D * D; // [256,512]

    float* ws = (float*)d_ws;
    const size_t BD = (size_t)BATCH * D;                 // 131072
    float* qb    = ws;
    float* kb    = ws + BD;
    float* vb    = ws + 2 * BD;
    float* ob    = ws + 3 * BD;
    float* h_pre = ws + 4 * BD;

    // 1) projections q,k,v,o (o fused with sigmoid+bias)
    proj_gemm<<<dim3(D / 64, BATCH / 64, 4), 256, 0, stream>>>(
        x_t, Wq, Wk, Wv, Wo_w, Wo_b, qb, kb, vb, ob);

    // 2) gates + n_t + C update + retrieval, 8 blocks per batch for TLP
    cstream<<<dim3(BATCH * 8), 256, 0, stream>>>(
        x_t, n_prev, C_prev, wi_w, wi_b, wf_w, wf_b,
        qb, kb, vb, ob, out_C, out_n, h_pre);

    // 3) LayerNorm -> h_t
    ln_kernel<<<dim3(BATCH), 256, 0, stream>>>(h_pre, ln_g, ln_b, out_h);
}

// Round 5
// 485.972 us; speedup vs baseline: 1.2285x; 1.0675x over previous
//
#include <hip/hip_runtime.h>
#include <math.h>

#define D 512
#define BATCH 256

// ---------------- block reduce (256 threads = 4 waves) ----------------
__device__ __forceinline__ float blockReduceSum(float val, float* smem) {
#pragma unroll
    for (int off = 32; off > 0; off >>= 1)
        val += __shfl_down(val, off, 64);
    int lane = threadIdx.x & 63;
    int w = threadIdx.x >> 6;
    __syncthreads();
    if (lane == 0) smem[w] = val;
    __syncthreads();
    return smem[0] + smem[1] + smem[2] + smem[3];
}

// ---------------- kernel 1: projections Y = X @ W^T (+ sigmoid/bias for o) ----
// X [256,512], W [512,512] row-major. THIS ROUND: BM=32 (was 64), BN=64, BK=32,
// 2x4 micro — grid 8x8x4 = 256 blocks so all 256 CUs are covered (was 128
// blocks = half the chip idle). Load/compute pattern otherwise identical to
// the verified 64x64 kernel.
__global__ __launch_bounds__(256) void proj_gemm(
    const float* __restrict__ X,
    const float* __restrict__ Wq, const float* __restrict__ Wk,
    const float* __restrict__ Wv, const float* __restrict__ Wo,
    const float* __restrict__ Wo_b,
    float* __restrict__ qb, float* __restrict__ kb,
    float* __restrict__ vb, float* __restrict__ ob)
{
    const int mat = blockIdx.z;
    const float* W = (mat == 0) ? Wq : (mat == 1) ? Wk : (mat == 2) ? Wv : Wo;
    float* Y = (mat == 0) ? qb : (mat == 1) ? kb : (mat == 2) ? vb : ob;

    const int m0 = blockIdx.y * 32;
    const int n0 = blockIdx.x * 64;

    __shared__ float Xs[32][33];
    __shared__ float Ws[64][33];

    const int t = threadIdx.x;
    const int lr = t >> 3;          // 0..31 (tile row for loading)
    const int lc = (t & 7) * 4;     // k offset 0,4,..,28
    const int ty = t >> 4;          // 0..15
    const int tx = t & 15;          // 0..15

    float acc[2][4] = {};

    for (int k0 = 0; k0 < D; k0 += 32) {
        float4 xa = *(const float4*)&X[(size_t)(m0 + lr) * D + k0 + lc];
        float4 wa = *(const float4*)&W[(size_t)(n0 + lr) * D + k0 + lc];
        float4 wb = *(const float4*)&W[(size_t)(n0 + lr + 32) * D + k0 + lc];
        __syncthreads();
        Xs[lr][lc + 0] = xa.x; Xs[lr][lc + 1] = xa.y; Xs[lr][lc + 2] = xa.z; Xs[lr][lc + 3] = xa.w;
        Ws[lr][lc + 0] = wa.x; Ws[lr][lc + 1] = wa.y; Ws[lr][lc + 2] = wa.z; Ws[lr][lc + 3] = wa.w;
        Ws[lr + 32][lc + 0] = wb.x; Ws[lr + 32][lc + 1] = wb.y; Ws[lr + 32][lc + 2] = wb.z; Ws[lr + 32][lc + 3] = wb.w;
        __syncthreads();
#pragma unroll
        for (int kk = 0; kk < 32; ++kk) {
            float a0 = Xs[ty * 2 + 0][kk];
            float a1 = Xs[ty * 2 + 1][kk];
            float b0 = Ws[tx * 4 + 0][kk];
            float b1 = Ws[tx * 4 + 1][kk];
            float b2 = Ws[tx * 4 + 2][kk];
            float b3 = Ws[tx * 4 + 3][kk];
            acc[0][0] += a0 * b0; acc[0][1] += a0 * b1; acc[0][2] += a0 * b2; acc[0][3] += a0 * b3;
            acc[1][0] += a1 * b0; acc[1][1] += a1 * b1; acc[1][2] += a1 * b2; acc[1][3] += a1 * b3;
        }
    }

#pragma unroll
    for (int i = 0; i < 2; ++i) {
        int row = m0 + ty * 2 + i;
#pragma unroll
        for (int j = 0; j < 4; ++j) {
            int col = n0 + tx * 4 + j;
            float y = acc[i][j];
            if (mat == 3) y = 1.0f / (1.0f + expf(-(y + Wo_b[col])));
            Y[(size_t)row * D + col] = y;
        }
    }
}

// ---------------- kernel 2: gates + n_t + nq (one block per b) ----------------
// (R0 champion, verbatim)
__global__ __launch_bounds__(256) void gates_n(
    const float* __restrict__ x, const float* __restrict__ n_prev,
    const float* __restrict__ wi_w, const float* __restrict__ wi_b,
    const float* __restrict__ wf_w, const float* __restrict__ wf_b,
    const float* __restrict__ qb, const float* __restrict__ kb,
    float* __restrict__ out_n,
    float* __restrict__ it_buf, float* __restrict__ ft_buf,
    float* __restrict__ invnq_buf)
{
    __shared__ float red[4];
    const int b = blockIdx.x;
    const int t = threadIdx.x;
    const float* xb = x + (size_t)b * D;

    float x0 = xb[t], x1 = xb[t + 256];
    float si = x0 * wi_w[t] + x1 * wi_w[t + 256];
    float sf = x0 * wf_w[t] + x1 * wf_w[t + 256];
    si = blockReduceSum(si, red);
    sf = blockReduceSum(sf, red);
    float i_t = fminf(expf(si + wi_b[0]), 50.0f);
    float f_t = 1.0f / (1.0f + expf(-(sf + wf_b[0])));

    const float* npv = n_prev + (size_t)b * D;
    const float* kk = kb + (size_t)b * D;
    const float* qq = qb + (size_t)b * D;
    float n0 = f_t * npv[t] + i_t * kk[t];
    float n1 = f_t * npv[t + 256] + i_t * kk[t + 256];
    out_n[(size_t)b * D + t] = n0;
    out_n[(size_t)b * D + t + 256] = n1;

    float nq = blockReduceSum(n0 * qq[t] + n1 * qq[t + 256], red);
    if (t == 0) {
        it_buf[b] = i_t;
        ft_buf[b] = f_t;
        invnq_buf[b] = 1.0f / fmaxf(fabsf(nq), 1.0f);
    }
}

// ---------------- kernel 3: C_t update + retrieval (one wave per row) ---------
// (R0 champion, verbatim: 32768 tiny blocks, plain loads AND plain stores,
// in-loop serial shuffle. Empirically the fastest C-stream across R0-R4:
// ~135us = 4.0 TB/s effective; every "refinement" (NT stores, register k/q,
// wave-owns-many-rows, deferred reductions) regressed it. Do not touch.)
__global__ __launch_bounds__(256) void cupdate(
    const float* __restrict__ C_prev,
    const float* __restrict__ kb, const float* __restrict__ qb,
    const float* __restrict__ vb, const float* __restrict__ ob,
    const float* __restrict__ it_buf, const float* __restrict__ ft_buf,
    const float* __restrict__ invnq_buf,
    float* __restrict__ out_C, float* __restrict__ h_pre)
{
    const int row = blockIdx.x * 4 + (threadIdx.x >> 6);   // b*512 + i
    const int lane = threadIdx.x & 63;
    const int b = row >> 9;

    const float f = ft_buf[b];
    const float a = it_buf[b] * vb[row];

    const float4* Cp = (const float4*)C_prev + (size_t)row * 128;
    float4* Ct = (float4*)out_C + (size_t)row * 128;
    const float4* k4 = (const float4*)kb + (size_t)b * 128;
    const float4* q4 = (const float4*)qb + (size_t)b * 128;

    float acc = 0.0f;
#pragma unroll
    for (int j = 0; j < 2; ++j) {
        int idx = lane + j * 64;
        float4 c = Cp[idx];
        float4 kv = k4[idx];
        float4 qv = q4[idx];
        float4 r;
        r.x = f * c.x + a * kv.x;
        r.y = f * c.y + a * kv.y;
        r.z = f * c.z + a * kv.z;
        r.w = f * c.w + a * kv.w;
        Ct[idx] = r;
        acc += r.x * qv.x + r.y * qv.y + r.z * qv.z + r.w * qv.w;
    }
#pragma unroll
    for (int off = 32; off > 0; off >>= 1)
        acc += __shfl_down(acc, off, 64);
    if (lane == 0)
        h_pre[row] = acc * ob[row] * invnq_buf[b];
}

// ---------------- kernel 4: LayerNorm epilogue (one block per b) --------------
// (R0 champion, verbatim)
__global__ __launch_bounds__(256) void ln_kernel(
    const float* __restrict__ h_pre,
    const float* __restrict__ g, const float* __restrict__ be,
    float* __restrict__ out_h)
{
    __shared__ float red[4];
    const int b = blockIdx.x;
    const int t = threadIdx.x;
    const float* h = h_pre + (size_t)b * D;
    float h0 = h[t], h1 = h[t + 256];
    float mu = blockReduceSum(h0 + h1, red) * (1.0f / 512.0f);
    float d0 = h0 - mu, d1 = h1 - mu;
    float var = blockReduceSum(d0 * d0 + d1 * d1, red) * (1.0f / 512.0f);
    float rstd = rsqrtf(var + 1e-5f);
    out_h[(size_t)b * D + t] = d0 * rstd * g[t] + be[t];
    out_h[(size_t)b * D + t + 256] = d1 * rstd * g[t + 256] + be[t + 256];
}

// ---------------- launcher ----------------------------------------------------
extern "C" void kernel_launch(void* const* d_in, const int* in_sizes, int n_in,
                              void* d_out, int out_size, void* d_ws, size_t ws_size,
                              hipStream_t stream) {
    const float* x_t    = (const float*)d_in[0];
    const float* C_prev = (const float*)d_in[1];
    const float* n_prev = (const float*)d_in[2];
    const float* Wq     = (const float*)d_in[3];
    const float* Wk     = (const float*)d_in[4];
    const float* Wv     = (const float*)d_in[5];
    const float* wi_w   = (const float*)d_in[6];
    const float* wi_b   = (const float*)d_in[7];
    const float* wf_w   = (const float*)d_in[8];
    const float* wf_b   = (const float*)d_in[9];
    const float* Wo_w   = (const float*)d_in[10];
    const float* Wo_b   = (const float*)d_in[11];
    const float* ln_g   = (const float*)d_in[12];
    const float* ln_b   = (const float*)d_in[13];

    float* out = (float*)d_out;
    float* out_h = out;                                  // [256,512]
    float* out_C = out + (size_t)BATCH * D;              // [256,512,512]
    float* out_n = out + (size_t)BATCH * D + (size_t)BATCH * D * D; // [256,512]

    float* ws = (float*)d_ws;
    const size_t BD = (size_t)BATCH * D;                 // 131072
    float* qb      = ws;
    float* kb      = ws + BD;
    float* vb      = ws + 2 * BD;
    float* ob      = ws + 3 * BD;
    float* h_pre   = ws + 4 * BD;
    float* it_buf  = ws + 5 * BD;
    float* ft_buf  = ws + 5 * BD + BATCH;
    float* invnq_b = ws + 5 * BD + 2 * BATCH;

    // 1) projections q,k,v,o — BM=32: grid 8x8x4 = 256 blocks (full chip)
    proj_gemm<<<dim3(D / 64, BATCH / 32, 4), 256, 0, stream>>>(
        x_t, Wq, Wk, Wv, Wo_w, Wo_b, qb, kb, vb, ob);

    // 2) gates + n_t + 1/max(|nq|,1)
    gates_n<<<dim3(BATCH), 256, 0, stream>>>(
        x_t, n_prev, wi_w, wi_b, wf_w, wf_b, qb, kb, out_n, it_buf, ft_buf, invnq_b);

    // 3) C_t = f*C_prev + (i*v) k^T, fused retrieval h_pre = o*(C_t q)/max(|nq|,1)
    cupdate<<<dim3(BATCH * D / 4), 256, 0, stream>>>(
        C_prev, kb, qb, vb, ob, it_buf, ft_buf, invnq_b, out_C, h_pre);

    // 4) LayerNorm -> h_t
    ln_kernel<<<dim3(BATCH), 256, 0, stream>>>(h_pre, ln_g, ln_b, out_h);
}